// Round 1
// baseline (584.169 us; speedup 1.0000x reference)
//
#include <hip/hip_runtime.h>
#include <stdint.h>

// Problem constants (static per reference)
#define NG    256    // graphs
#define NPG   128    // nodes per graph
#define PP    8      // perturbations
#define IND   64     // input dim
#define HID   128    // hidden
#define OUTD  10     // classes

typedef short bf16x8 __attribute__((ext_vector_type(8)));
typedef float f32x4  __attribute__((ext_vector_type(4)));

static __device__ __forceinline__ unsigned short f2bf(float f) {
    unsigned int u = __float_as_uint(f);
    u += 0x7FFFu + ((u >> 16) & 1u);
    return (unsigned short)(u >> 16);
}

static __device__ __forceinline__ f32x4 mfma16(bf16x8 a, bf16x8 b, f32x4 c) {
    return __builtin_amdgcn_mfma_f32_16x16x32_bf16(a, b, c, 0, 0, 0);
}

// 8 consecutive fp32 -> bf16x8 (works for LDS or global generic pointers)
static __device__ __forceinline__ bf16x8 cvt8(const float* p) {
    float4 lo = *(const float4*)p;
    float4 hi = *(const float4*)(p + 4);
    bf16x8 v;
    v[0] = (short)f2bf(lo.x); v[1] = (short)f2bf(lo.y);
    v[2] = (short)f2bf(lo.z); v[3] = (short)f2bf(lo.w);
    v[4] = (short)f2bf(hi.x); v[5] = (short)f2bf(hi.y);
    v[6] = (short)f2bf(hi.z); v[7] = (short)f2bf(hi.w);
    return v;
}

// async global->LDS, 4 bytes per lane: lane i's 4B lands at lptr + lane*4
static __device__ __forceinline__ void async_load4(const float* gptr, float* lptr) {
    __builtin_amdgcn_global_load_lds(
        (const __attribute__((address_space(1))) unsigned int*)gptr,
        (__attribute__((address_space(3))) unsigned int*)lptr,
        4, 0, 0);
}

// ws layout (shorts):
//   [0)      W1t  128x64   (Wt[out][in])
//   [8192)   W2t  128x128
//   [24576)  Wg1t 128x128
//   [40960)  Wg2t 128x128
//   [57344)  Wb1t 128x128
//   [73728)  Wb2t 128x128
//   [90112)  cnt  256 x u32 (zeroed each iteration by prep; ws is poisoned)
//   [90624)  agg  32768x128 bf16 (phase-A output; byte offset 181248, 16B-aligned)
#define CNT_SHORT 90112
#define AGG_OFF   90624

#define LSTR 136   // bf16 LDS row stride (272 B): 2-way bank aliasing only (free)
#define XSTR 68    // fp32 LDS row stride (272 B): same property

// ---------------------------------------------------------------------------
// Kernel 0: convert + transpose weights (coalesced writes; src stays in L2)
//           + zero the per-graph completion counters (ws is re-poisoned).
// ---------------------------------------------------------------------------
__global__ void prep_weights(const float* __restrict__ Wl1, const float* __restrict__ Wl2,
                             const float* __restrict__ Wg1, const float* __restrict__ Wg2,
                             const float* __restrict__ Wb1, const float* __restrict__ Wb2,
                             unsigned short* __restrict__ ws) {
    int e = blockIdx.x * blockDim.x + threadIdx.x;
    if (e < NG) ((unsigned int*)(ws + CNT_SHORT))[e] = 0u;
    if (e < 8192) {
        int n = e >> 6, k = e & 63;
        ws[e] = f2bf(Wl1[k * HID + n]);
        return;
    }
    int e2 = e - 8192;
    int m = e2 >> 14;
    int idx = e2 & 16383;
    int n = idx >> 7, k = idx & 127;
    const float* src;
    if      (m == 0) src = Wl2;
    else if (m == 1) src = Wg1;
    else if (m == 2) src = Wg2;
    else if (m == 3) src = Wb1;
    else             src = Wb2;
    ws[8192 + m * 16384 + idx] = f2bf(src[k * HID + n]);
}

// Shared-memory union: phase A (local MLP) vs phase B (global layers + decoder)
union SMem {
    struct {
        float xbuf[128 * XSTR];                 // 34816 B
        unsigned short h1buf[2][16 * LSTR];     //  8704 B
    } a;                                        // 43520 B total
    struct {
        unsigned short buf0[64 * LSTR];         // 17408 B
        unsigned short buf1[64 * LSTR];         // 17408 B
        float pool[HID];
        float z[64];
        float zz[OUTD];
    } b;                                        // 35624 B total
};

// ---------------------------------------------------------------------------
// Fused kernel: phase A = local MLP + perturbation-sum (block = (g, 16-node
// tile), 2048 blocks x 256 threads). Each block then bumps a per-graph
// device-scope counter; the 8th (last) sibling block of graph g continues
// into phase B: 4x (Linear+ReLU) over the graph's 128 agg rows (two 64-row
// halves, LDS-resident), global_add_pool, decoder + log_softmax.
// Phase B overlaps other graphs' phase A — no device-wide drain.
// ---------------------------------------------------------------------------
__global__ __launch_bounds__(256, 3) void fused_main(
    const float* __restrict__ x,
    const unsigned short* __restrict__ wt,
    const float* __restrict__ bl1, const float* __restrict__ bl2,
    const float* __restrict__ bg1, const float* __restrict__ bg2,
    const float* __restrict__ bb1, const float* __restrict__ bb2,
    const float* __restrict__ Wd1, const float* __restrict__ bd1,
    const float* __restrict__ Wd2, const float* __restrict__ bd2,
    unsigned short* __restrict__ aggbuf,
    unsigned int* __restrict__ cnt,
    float* __restrict__ out)
{
    __shared__ SMem sm;
    __shared__ int win;

    const int g    = blockIdx.x >> 3;
    const int nt   = blockIdx.x & 7;
    const int tid  = threadIdx.x;
    const int wave = tid >> 6;
    const int lane = tid & 63;
    const int q    = lane >> 4;
    const int r    = lane & 15;
    const int ot0  = wave * 2;     // this wave's out-tiles

    // ======================= phase A: local MLP ============================
    {
        float* xbuf = sm.a.xbuf;

        // ---- issue all x staging first (row s = p*16+rr of the block's slab) ----
        {
            const float* xbase = x + ((size_t)g * 1024 + nt * 16) * IND + lane;
            for (int s = wave; s < 128; s += 4) {
                int p = s >> 4, rr = s & 15;
                async_load4(xbase + (size_t)(p * 128 + rr) * IND, &xbuf[s * XSTR]);
            }
        }

        // ---- weight fragments into registers (overlaps with x staging) ----
        bf16x8 w1f[2][2];
#pragma unroll
        for (int t = 0; t < 2; ++t)
#pragma unroll
            for (int ks = 0; ks < 2; ++ks)
                w1f[t][ks] = *(const bf16x8*)(wt + ((ot0 + t) * 16 + r) * 64 + ks * 32 + q * 8);

        const unsigned short* w2t = wt + 8192;
        bf16x8 w2f[2][4];
#pragma unroll
        for (int t = 0; t < 2; ++t)
#pragma unroll
            for (int ks = 0; ks < 4; ++ks)
                w2f[t][ks] = *(const bf16x8*)(w2t + ((ot0 + t) * 16 + r) * 128 + ks * 32 + q * 8);

        float4 b1s[2], b2s[2];
#pragma unroll
        for (int t = 0; t < 2; ++t) {
            int ob = (ot0 + t) * 16 + q * 4;
            b1s[t] = *(const float4*)(bl1 + ob);
            b2s[t] = *(const float4*)(bl2 + ob);
        }

        f32x4 agg[2];
        agg[0] = (f32x4){0.f, 0.f, 0.f, 0.f};
        agg[1] = (f32x4){0.f, 0.f, 0.f, 0.f};

        __syncthreads();   // drains vmcnt: all x rows now in LDS

        for (int p = 0; p < PP; ++p) {
            unsigned short* h1 = sm.a.h1buf[p & 1];

            // layer 1 (K=64) from xbuf
            f32x4 acc[2];
            acc[0] = (f32x4){0.f, 0.f, 0.f, 0.f};
            acc[1] = (f32x4){0.f, 0.f, 0.f, 0.f};
#pragma unroll
            for (int ks = 0; ks < 2; ++ks) {
                bf16x8 xf = cvt8(&xbuf[(p * 16 + r) * XSTR + ks * 32 + q * 8]);
                acc[0] = mfma16(w1f[0][ks], xf, acc[0]);
                acc[1] = mfma16(w1f[1][ks], xf, acc[1]);
            }
#pragma unroll
            for (int t = 0; t < 2; ++t) {
                int ob = (ot0 + t) * 16 + q * 4;
                ushort4 v;
                v.x = f2bf(fmaxf(acc[t][0] + b1s[t].x, 0.f));
                v.y = f2bf(fmaxf(acc[t][1] + b1s[t].y, 0.f));
                v.z = f2bf(fmaxf(acc[t][2] + b1s[t].z, 0.f));
                v.w = f2bf(fmaxf(acc[t][3] + b1s[t].w, 0.f));
                *(ushort4*)(h1 + r * LSTR + ob) = v;
            }
            __syncthreads();

            // layer 2 (K=128), relu-accumulate into agg
            f32x4 acc2[2];
            acc2[0] = (f32x4){0.f, 0.f, 0.f, 0.f};
            acc2[1] = (f32x4){0.f, 0.f, 0.f, 0.f};
#pragma unroll
            for (int ks = 0; ks < 4; ++ks) {
                bf16x8 hf = *(const bf16x8*)(h1 + r * LSTR + ks * 32 + q * 8);
                acc2[0] = mfma16(w2f[0][ks], hf, acc2[0]);
                acc2[1] = mfma16(w2f[1][ks], hf, acc2[1]);
            }
#pragma unroll
            for (int t = 0; t < 2; ++t) {
                agg[t][0] += fmaxf(acc2[t][0] + b2s[t].x, 0.f);
                agg[t][1] += fmaxf(acc2[t][1] + b2s[t].y, 0.f);
                agg[t][2] += fmaxf(acc2[t][2] + b2s[t].z, 0.f);
                agg[t][3] += fmaxf(acc2[t][3] + b2s[t].w, 0.f);
            }
            // double-buffered h1 -> one barrier per p is sufficient
        }

        // stage agg (bf16) in h1buf[0]; safe without a barrier (p=7 barrier
        // already guarantees every wave finished its buf0 reads of p=6)
#pragma unroll
        for (int t = 0; t < 2; ++t) {
            int ob = (ot0 + t) * 16 + q * 4;
            ushort4 v;
            v.x = f2bf(agg[t][0]);
            v.y = f2bf(agg[t][1]);
            v.z = f2bf(agg[t][2]);
            v.w = f2bf(agg[t][3]);
            *(ushort4*)(sm.a.h1buf[0] + r * LSTR + ob) = v;
        }
        __syncthreads();

        // coalesced writeback: 256 threads x 16 B = one full 4 KB tile
        {
            int row = tid >> 4, c8 = (tid & 15) * 8;
            bf16x8 v = *(const bf16x8*)(sm.a.h1buf[0] + row * LSTR + c8);
            *(bf16x8*)(aggbuf + ((size_t)(g * NPG + nt * 16 + row)) * HID + c8) = v;
        }
    }

    // ============== per-graph completion (device-scope, cross-XCD) =========
    __threadfence();                 // release: this thread's agg stores
    __syncthreads();                 // order all block threads before the RMW
    if (tid == 0) {
        unsigned int old = atomicAdd(&cnt[g], 1u);   // device-scope (G12)
        win = (old == 7u);
    }
    __syncthreads();
    if (!win) return;
    __threadfence();                 // acquire: make siblings' agg visible

    // ================= phase B: global layers + pool (winner) ==============
    float s_tot[2][4];
#pragma unroll
    for (int t = 0; t < 2; ++t)
#pragma unroll
        for (int i = 0; i < 4; ++i) s_tot[t][i] = 0.f;

    for (int h = 0; h < 2; ++h) {
        // stage this half-graph's 64 agg rows (16 KB) coalesced
        const unsigned short* ag = aggbuf + ((size_t)g * NPG + h * 64) * HID;
#pragma unroll
        for (int it = 0; it < 4; ++it) {
            int c = tid + it * 256;
            int row = c >> 4, c8 = (c & 15) * 8;
            *(bf16x8*)(sm.b.buf0 + row * LSTR + c8) = *(const bf16x8*)(ag + (size_t)row * HID + c8);
        }
        __syncthreads();

        int cur = 0;
#pragma unroll
        for (int l = 0; l < 4; ++l) {
            const unsigned short* wl = wt + 24576 + l * 16384;
            const float* bl = (l == 0) ? bg1 : (l == 1) ? bg2 : (l == 2) ? bb1 : bb2;

            bf16x8 wf[2][4];
#pragma unroll
            for (int t = 0; t < 2; ++t)
#pragma unroll
                for (int ks = 0; ks < 4; ++ks)
                    wf[t][ks] = *(const bf16x8*)(wl + ((ot0 + t) * 16 + r) * 128 + ks * 32 + q * 8);

            unsigned short* Xb = cur ? sm.b.buf1 : sm.b.buf0;
            unsigned short* Yb = cur ? sm.b.buf0 : sm.b.buf1;

            f32x4 acc[2][4];
#pragma unroll
            for (int t = 0; t < 2; ++t)
#pragma unroll
                for (int j = 0; j < 4; ++j)
                    acc[t][j] = (f32x4){0.f, 0.f, 0.f, 0.f};

#pragma unroll
            for (int ks = 0; ks < 4; ++ks) {
#pragma unroll
                for (int j = 0; j < 4; ++j) {
                    int row = j * 16 + r;
                    bf16x8 xf = *(const bf16x8*)(Xb + row * LSTR + ks * 32 + q * 8);
                    acc[0][j] = mfma16(wf[0][ks], xf, acc[0][j]);
                    acc[1][j] = mfma16(wf[1][ks], xf, acc[1][j]);
                }
            }

            if (l < 3) {
#pragma unroll
                for (int t = 0; t < 2; ++t) {
                    int ob = (ot0 + t) * 16 + q * 4;
                    float4 bs = *(const float4*)(bl + ob);
#pragma unroll
                    for (int j = 0; j < 4; ++j) {
                        int row = j * 16 + r;
                        ushort4 v;
                        v.x = f2bf(fmaxf(acc[t][j][0] + bs.x, 0.f));
                        v.y = f2bf(fmaxf(acc[t][j][1] + bs.y, 0.f));
                        v.z = f2bf(fmaxf(acc[t][j][2] + bs.z, 0.f));
                        v.w = f2bf(fmaxf(acc[t][j][3] + bs.w, 0.f));
                        *(ushort4*)(Yb + row * LSTR + ob) = v;
                    }
                }
                __syncthreads();
                cur ^= 1;
            } else {
                float s[2][4];
#pragma unroll
                for (int t = 0; t < 2; ++t) {
                    int ob = (ot0 + t) * 16 + q * 4;
                    float4 bs = *(const float4*)(bl + ob);
                    s[t][0] = s[t][1] = s[t][2] = s[t][3] = 0.f;
#pragma unroll
                    for (int j = 0; j < 4; ++j) {
                        s[t][0] += fmaxf(acc[t][j][0] + bs.x, 0.f);
                        s[t][1] += fmaxf(acc[t][j][1] + bs.y, 0.f);
                        s[t][2] += fmaxf(acc[t][j][2] + bs.z, 0.f);
                        s[t][3] += fmaxf(acc[t][j][3] + bs.w, 0.f);
                    }
                }
#pragma unroll
                for (int m = 1; m < 16; m <<= 1) {
#pragma unroll
                    for (int t = 0; t < 2; ++t)
#pragma unroll
                        for (int i = 0; i < 4; ++i)
                            s[t][i] += __shfl_xor(s[t][i], m, 64);
                }
#pragma unroll
                for (int t = 0; t < 2; ++t)
#pragma unroll
                    for (int i = 0; i < 4; ++i)
                        s_tot[t][i] += s[t][i];
            }
        }
        // no barrier needed before next h: l=2's barrier already separates the
        // last buf0 access; h-staging writes buf0 while l=3 only reads buf1.
        __syncthreads();
    }

    if (r == 0) {
#pragma unroll
        for (int t = 0; t < 2; ++t)
#pragma unroll
            for (int i = 0; i < 4; ++i)
                sm.b.pool[(ot0 + t) * 16 + q * 4 + i] = s_tot[t][i];  // exclusive cols/wave
    }
    __syncthreads();

    // ===================== decoder + log_softmax (winner) ==================
    if (tid < 64) {
        float a0 = bd1[tid], a1 = 0.f, a2 = 0.f, a3 = 0.f;
#pragma unroll
        for (int k = 0; k < 128; k += 4) {
            a0 += sm.b.pool[k]     * Wd1[(k)     * 64 + tid];
            a1 += sm.b.pool[k + 1] * Wd1[(k + 1) * 64 + tid];
            a2 += sm.b.pool[k + 2] * Wd1[(k + 2) * 64 + tid];
            a3 += sm.b.pool[k + 3] * Wd1[(k + 3) * 64 + tid];
        }
        sm.b.z[tid] = fmaxf((a0 + a1) + (a2 + a3), 0.f);
    }
    __syncthreads();
    if (tid < OUTD) {
        float b0 = bd2[tid], b1 = 0.f;
#pragma unroll
        for (int k = 0; k < 64; k += 2) {
            b0 += sm.b.z[k]     * Wd2[(k)     * OUTD + tid];
            b1 += sm.b.z[k + 1] * Wd2[(k + 1) * OUTD + tid];
        }
        sm.b.zz[tid] = b0 + b1;
    }
    __syncthreads();
    if (tid == 0) {
        float m = -1e30f;
#pragma unroll
        for (int j = 0; j < OUTD; ++j) m = fmaxf(m, sm.b.zz[j]);
        float ssum = 0.f;
#pragma unroll
        for (int j = 0; j < OUTD; ++j) ssum += expf(sm.b.zz[j] - m);
        float ls = logf(ssum);
#pragma unroll
        for (int j = 0; j < OUTD; ++j) out[g * OUTD + j] = sm.b.zz[j] - m - ls;
    }
}

extern "C" void kernel_launch(void* const* d_in, const int* in_sizes, int n_in,
                              void* d_out, int out_size, void* d_ws, size_t ws_size,
                              hipStream_t stream) {
    const float* x   = (const float*)d_in[0];
    // d_in[1] = ptr (unused; structure is static)
    const float* Wl1 = (const float*)d_in[2];
    const float* bl1 = (const float*)d_in[3];
    const float* Wl2 = (const float*)d_in[4];
    const float* bl2 = (const float*)d_in[5];
    const float* Wg1 = (const float*)d_in[6];
    const float* bg1 = (const float*)d_in[7];
    const float* Wg2 = (const float*)d_in[8];
    const float* bg2 = (const float*)d_in[9];
    const float* Wb1 = (const float*)d_in[10];
    const float* bb1 = (const float*)d_in[11];
    const float* Wb2 = (const float*)d_in[12];
    const float* bb2 = (const float*)d_in[13];
    const float* Wd1 = (const float*)d_in[14];
    const float* bd1 = (const float*)d_in[15];
    const float* Wd2 = (const float*)d_in[16];
    const float* bd2 = (const float*)d_in[17];

    unsigned short* ws  = (unsigned short*)d_ws;
    unsigned int*   cnt = (unsigned int*)(ws + CNT_SHORT);
    unsigned short* agg = ws + AGG_OFF;

    prep_weights<<<352, 256, 0, stream>>>(Wl1, Wl2, Wg1, Wg2, Wb1, Wb2, ws);
    fused_main<<<NG * 8, 256, 0, stream>>>(x, ws, bl1, bl2, bg1, bg2, bb1, bb2,
                                           Wd1, bd1, Wd2, bd2, agg, cnt, (float*)d_out);
}

// Round 2
// 158.495 us; speedup vs baseline: 3.6857x; 3.6857x over previous
//
#include <hip/hip_runtime.h>
#include <stdint.h>

// Problem constants (static per reference)
#define NG    256    // graphs
#define NPG   128    // nodes per graph
#define PP    8      // perturbations
#define IND   64     // input dim
#define HID   128    // hidden
#define OUTD  10     // classes

typedef short bf16x8 __attribute__((ext_vector_type(8)));
typedef float f32x4  __attribute__((ext_vector_type(4)));

static __device__ __forceinline__ unsigned short f2bf(float f) {
    unsigned int u = __float_as_uint(f);
    u += 0x7FFFu + ((u >> 16) & 1u);
    return (unsigned short)(u >> 16);
}

static __device__ __forceinline__ f32x4 mfma16(bf16x8 a, bf16x8 b, f32x4 c) {
    return __builtin_amdgcn_mfma_f32_16x16x32_bf16(a, b, c, 0, 0, 0);
}

// 8 consecutive fp32 -> bf16x8 (works for LDS or global generic pointers)
static __device__ __forceinline__ bf16x8 cvt8(const float* p) {
    float4 lo = *(const float4*)p;
    float4 hi = *(const float4*)(p + 4);
    bf16x8 v;
    v[0] = (short)f2bf(lo.x); v[1] = (short)f2bf(lo.y);
    v[2] = (short)f2bf(lo.z); v[3] = (short)f2bf(lo.w);
    v[4] = (short)f2bf(hi.x); v[5] = (short)f2bf(hi.y);
    v[6] = (short)f2bf(hi.z); v[7] = (short)f2bf(hi.w);
    return v;
}

// async global->LDS, 4 bytes per lane: lane i's 4B lands at lptr + lane*4
static __device__ __forceinline__ void async_load4(const float* gptr, float* lptr) {
    __builtin_amdgcn_global_load_lds(
        (const __attribute__((address_space(1))) unsigned int*)gptr,
        (__attribute__((address_space(3))) unsigned int*)lptr,
        4, 0, 0);
}

// ws layout (shorts):
//   [0)      W1t  128x64   (Wt[out][in])
//   [8192)   W2t  128x128
//   [24576)  Wg1t 128x128
//   [40960)  Wg2t 128x128
//   [57344)  Wb1t 128x128
//   [73728)  Wb2t 128x128
//   [90112)  agg  32768x128 bf16 (phase-A output)
#define AGG_OFF   90112

#define LSTR 136   // bf16 LDS row stride (272 B): 2-way bank aliasing only (free)
#define XSTR 68    // fp32 LDS row stride (272 B): same property

// ---------------------------------------------------------------------------
// Kernel 0: convert + transpose weights (coalesced writes; src stays in L2)
// ---------------------------------------------------------------------------
__global__ void prep_weights(const float* __restrict__ Wl1, const float* __restrict__ Wl2,
                             const float* __restrict__ Wg1, const float* __restrict__ Wg2,
                             const float* __restrict__ Wb1, const float* __restrict__ Wb2,
                             unsigned short* __restrict__ ws) {
    int e = blockIdx.x * blockDim.x + threadIdx.x;
    if (e < 8192) {
        int n = e >> 6, k = e & 63;
        ws[e] = f2bf(Wl1[k * HID + n]);
        return;
    }
    int e2 = e - 8192;
    int m = e2 >> 14;
    int idx = e2 & 16383;
    int n = idx >> 7, k = idx & 127;
    const float* src;
    if      (m == 0) src = Wl2;
    else if (m == 1) src = Wg1;
    else if (m == 2) src = Wg2;
    else if (m == 3) src = Wb1;
    else             src = Wb2;
    ws[8192 + m * 16384 + idx] = f2bf(src[k * HID + n]);
}

// ---------------------------------------------------------------------------
// Kernel 1 (phase A): block = (g, 16-node tile). 2048 blocks x 256 threads.
// All 8 perturbations' x rows (32 KB fp32) staged to LDS asynchronously up
// front (32 global_load_lds per wave -> ~96 KB in flight per CU); the p-loop
// is then pure LDS+MFMA. agg written back coalesced via LDS staging.
// NO cross-block sync: agent-scope fences (buffer_wbl2/inv) are a full-L2
// flush per block on gfx950 and serialized the whole device in round 1.
// ---------------------------------------------------------------------------
__global__ __launch_bounds__(256, 3) void local_mlp(
    const float* __restrict__ x,
    const unsigned short* __restrict__ wt,
    const float* __restrict__ bl1, const float* __restrict__ bl2,
    unsigned short* __restrict__ aggbuf)
{
    __shared__ float xbuf[128 * XSTR];                 // 34816 B
    __shared__ unsigned short h1buf[2][16 * LSTR];     //  8704 B

    const int g    = blockIdx.x >> 3;
    const int nt   = blockIdx.x & 7;
    const int tid  = threadIdx.x;
    const int wave = tid >> 6;
    const int lane = tid & 63;
    const int q    = lane >> 4;
    const int r    = lane & 15;
    const int ot0  = wave * 2;     // this wave's out-tiles

    // ---- issue all x staging first (row s = p*16+rr of the block's slab) ----
    {
        const float* xbase = x + ((size_t)g * 1024 + nt * 16) * IND + lane;
        for (int s = wave; s < 128; s += 4) {
            int p = s >> 4, rr = s & 15;
            async_load4(xbase + (size_t)(p * 128 + rr) * IND, &xbuf[s * XSTR]);
        }
    }

    // ---- weight fragments into registers (overlaps with x staging) ----
    bf16x8 w1f[2][2];
#pragma unroll
    for (int t = 0; t < 2; ++t)
#pragma unroll
        for (int ks = 0; ks < 2; ++ks)
            w1f[t][ks] = *(const bf16x8*)(wt + ((ot0 + t) * 16 + r) * 64 + ks * 32 + q * 8);

    const unsigned short* w2t = wt + 8192;
    bf16x8 w2f[2][4];
#pragma unroll
    for (int t = 0; t < 2; ++t)
#pragma unroll
        for (int ks = 0; ks < 4; ++ks)
            w2f[t][ks] = *(const bf16x8*)(w2t + ((ot0 + t) * 16 + r) * 128 + ks * 32 + q * 8);

    float4 b1s[2], b2s[2];
#pragma unroll
    for (int t = 0; t < 2; ++t) {
        int ob = (ot0 + t) * 16 + q * 4;
        b1s[t] = *(const float4*)(bl1 + ob);
        b2s[t] = *(const float4*)(bl2 + ob);
    }

    f32x4 agg[2];
    agg[0] = (f32x4){0.f, 0.f, 0.f, 0.f};
    agg[1] = (f32x4){0.f, 0.f, 0.f, 0.f};

    __syncthreads();   // drains vmcnt: all x rows now in LDS

    for (int p = 0; p < PP; ++p) {
        unsigned short* h1 = h1buf[p & 1];

        // layer 1 (K=64) from xbuf
        f32x4 acc[2];
        acc[0] = (f32x4){0.f, 0.f, 0.f, 0.f};
        acc[1] = (f32x4){0.f, 0.f, 0.f, 0.f};
#pragma unroll
        for (int ks = 0; ks < 2; ++ks) {
            bf16x8 xf = cvt8(&xbuf[(p * 16 + r) * XSTR + ks * 32 + q * 8]);
            acc[0] = mfma16(w1f[0][ks], xf, acc[0]);
            acc[1] = mfma16(w1f[1][ks], xf, acc[1]);
        }
#pragma unroll
        for (int t = 0; t < 2; ++t) {
            int ob = (ot0 + t) * 16 + q * 4;
            ushort4 v;
            v.x = f2bf(fmaxf(acc[t][0] + b1s[t].x, 0.f));
            v.y = f2bf(fmaxf(acc[t][1] + b1s[t].y, 0.f));
            v.z = f2bf(fmaxf(acc[t][2] + b1s[t].z, 0.f));
            v.w = f2bf(fmaxf(acc[t][3] + b1s[t].w, 0.f));
            *(ushort4*)(h1 + r * LSTR + ob) = v;
        }
        __syncthreads();

        // layer 2 (K=128), relu-accumulate into agg
        f32x4 acc2[2];
        acc2[0] = (f32x4){0.f, 0.f, 0.f, 0.f};
        acc2[1] = (f32x4){0.f, 0.f, 0.f, 0.f};
#pragma unroll
        for (int ks = 0; ks < 4; ++ks) {
            bf16x8 hf = *(const bf16x8*)(h1 + r * LSTR + ks * 32 + q * 8);
            acc2[0] = mfma16(w2f[0][ks], hf, acc2[0]);
            acc2[1] = mfma16(w2f[1][ks], hf, acc2[1]);
        }
#pragma unroll
        for (int t = 0; t < 2; ++t) {
            agg[t][0] += fmaxf(acc2[t][0] + b2s[t].x, 0.f);
            agg[t][1] += fmaxf(acc2[t][1] + b2s[t].y, 0.f);
            agg[t][2] += fmaxf(acc2[t][2] + b2s[t].z, 0.f);
            agg[t][3] += fmaxf(acc2[t][3] + b2s[t].w, 0.f);
        }
        // double-buffered h1 -> one barrier per p is sufficient
    }

    // stage agg (bf16) in h1buf[0]; safe without a barrier (p=7 barrier already
    // guarantees every wave finished its buf0 reads of p=6)
#pragma unroll
    for (int t = 0; t < 2; ++t) {
        int ob = (ot0 + t) * 16 + q * 4;
        ushort4 v;
        v.x = f2bf(agg[t][0]);
        v.y = f2bf(agg[t][1]);
        v.z = f2bf(agg[t][2]);
        v.w = f2bf(agg[t][3]);
        *(ushort4*)(h1buf[0] + r * LSTR + ob) = v;
    }
    __syncthreads();

    // coalesced writeback: 256 threads x 16 B = one full 4 KB tile
    {
        int row = tid >> 4, c8 = (tid & 15) * 8;
        bf16x8 v = *(const bf16x8*)(h1buf[0] + row * LSTR + c8);
        *(bf16x8*)(aggbuf + ((size_t)(g * NPG + nt * 16 + row)) * HID + c8) = v;
    }
}

// ---------------------------------------------------------------------------
// Kernel 2: 4x (Linear+ReLU) on FULL graphs (128 rows in LDS), then
// global_add_pool + decoder + log_softmax in the same block.
// 256 blocks x 256 threads; wave w owns output columns [32w, 32w+32).
// Replaces the old half-graph global_layers + partial buffer + decoder_k:
// one less launch boundary, no partial round-trip, no cross-block comm.
// ---------------------------------------------------------------------------
__global__ __launch_bounds__(256) void global_decoder(
    const unsigned short* __restrict__ wt,
    const unsigned short* __restrict__ aggbuf,
    const float* __restrict__ bg1, const float* __restrict__ bg2,
    const float* __restrict__ bb1, const float* __restrict__ bb2,
    const float* __restrict__ Wd1, const float* __restrict__ bd1,
    const float* __restrict__ Wd2, const float* __restrict__ bd2,
    float* __restrict__ out)
{
    __shared__ unsigned short buf0[128 * LSTR];   // 34816 B
    __shared__ unsigned short buf1[128 * LSTR];   // 34816 B
    __shared__ float pool[HID];
    __shared__ float z[64];
    __shared__ float zz[OUTD];

    const int g    = blockIdx.x;
    const int tid  = threadIdx.x;
    const int wave = tid >> 6;
    const int lane = tid & 63;
    const int q    = lane >> 4;
    const int r    = lane & 15;
    const int ot0  = wave * 2;

    // stage this graph's 128 agg rows (32 KB) coalesced
    const unsigned short* ag = aggbuf + (size_t)g * NPG * HID;
#pragma unroll
    for (int it = 0; it < 8; ++it) {
        int c = tid + it * 256;
        int row = c >> 4, c8 = (c & 15) * 8;
        *(bf16x8*)(buf0 + row * LSTR + c8) = *(const bf16x8*)(ag + (size_t)row * HID + c8);
    }
    __syncthreads();

    int cur = 0;
#pragma unroll
    for (int l = 0; l < 4; ++l) {
        const unsigned short* wl = wt + 24576 + l * 16384;
        const float* bl = (l == 0) ? bg1 : (l == 1) ? bg2 : (l == 2) ? bb1 : bb2;

        bf16x8 wf[2][4];
#pragma unroll
        for (int t = 0; t < 2; ++t)
#pragma unroll
            for (int ks = 0; ks < 4; ++ks)
                wf[t][ks] = *(const bf16x8*)(wl + ((ot0 + t) * 16 + r) * 128 + ks * 32 + q * 8);

        unsigned short* Xb = cur ? buf1 : buf0;
        unsigned short* Yb = cur ? buf0 : buf1;

        f32x4 acc[2][8];
#pragma unroll
        for (int t = 0; t < 2; ++t)
#pragma unroll
            for (int j = 0; j < 8; ++j)
                acc[t][j] = (f32x4){0.f, 0.f, 0.f, 0.f};

#pragma unroll
        for (int ks = 0; ks < 4; ++ks) {
#pragma unroll
            for (int j = 0; j < 8; ++j) {
                int row = j * 16 + r;
                bf16x8 xf = *(const bf16x8*)(Xb + row * LSTR + ks * 32 + q * 8);
                acc[0][j] = mfma16(wf[0][ks], xf, acc[0][j]);
                acc[1][j] = mfma16(wf[1][ks], xf, acc[1][j]);
            }
        }

        if (l < 3) {
#pragma unroll
            for (int t = 0; t < 2; ++t) {
                int ob = (ot0 + t) * 16 + q * 4;
                float4 bs = *(const float4*)(bl + ob);
#pragma unroll
                for (int j = 0; j < 8; ++j) {
                    int row = j * 16 + r;
                    ushort4 v;
                    v.x = f2bf(fmaxf(acc[t][j][0] + bs.x, 0.f));
                    v.y = f2bf(fmaxf(acc[t][j][1] + bs.y, 0.f));
                    v.z = f2bf(fmaxf(acc[t][j][2] + bs.z, 0.f));
                    v.w = f2bf(fmaxf(acc[t][j][3] + bs.w, 0.f));
                    *(ushort4*)(Yb + row * LSTR + ob) = v;
                }
            }
            __syncthreads();
            cur ^= 1;
        } else {
            float s[2][4];
#pragma unroll
            for (int t = 0; t < 2; ++t) {
                int ob = (ot0 + t) * 16 + q * 4;
                float4 bs = *(const float4*)(bl + ob);
                s[t][0] = s[t][1] = s[t][2] = s[t][3] = 0.f;
#pragma unroll
                for (int j = 0; j < 8; ++j) {
                    s[t][0] += fmaxf(acc[t][j][0] + bs.x, 0.f);
                    s[t][1] += fmaxf(acc[t][j][1] + bs.y, 0.f);
                    s[t][2] += fmaxf(acc[t][j][2] + bs.z, 0.f);
                    s[t][3] += fmaxf(acc[t][j][3] + bs.w, 0.f);
                }
            }
#pragma unroll
            for (int m = 1; m < 16; m <<= 1) {
#pragma unroll
                for (int t = 0; t < 2; ++t)
#pragma unroll
                    for (int i = 0; i < 4; ++i)
                        s[t][i] += __shfl_xor(s[t][i], m, 64);
            }
            if (r == 0) {
#pragma unroll
                for (int t = 0; t < 2; ++t)
#pragma unroll
                    for (int i = 0; i < 4; ++i)
                        pool[(ot0 + t) * 16 + q * 4 + i] = s[t][i];  // exclusive cols/wave
            }
        }
    }
    __syncthreads();

    // ---- decoder + log_softmax ----
    if (tid < 64) {
        float a0 = bd1[tid], a1 = 0.f, a2 = 0.f, a3 = 0.f;
#pragma unroll
        for (int k = 0; k < 128; k += 4) {
            a0 += pool[k]     * Wd1[(k)     * 64 + tid];
            a1 += pool[k + 1] * Wd1[(k + 1) * 64 + tid];
            a2 += pool[k + 2] * Wd1[(k + 2) * 64 + tid];
            a3 += pool[k + 3] * Wd1[(k + 3) * 64 + tid];
        }
        z[tid] = fmaxf((a0 + a1) + (a2 + a3), 0.f);
    }
    __syncthreads();
    if (tid < OUTD) {
        float b0 = bd2[tid], b1 = 0.f;
#pragma unroll
        for (int k = 0; k < 64; k += 2) {
            b0 += z[k]     * Wd2[(k)     * OUTD + tid];
            b1 += z[k + 1] * Wd2[(k + 1) * OUTD + tid];
        }
        zz[tid] = b0 + b1;
    }
    __syncthreads();
    if (tid == 0) {
        float m = -1e30f;
#pragma unroll
        for (int j = 0; j < OUTD; ++j) m = fmaxf(m, zz[j]);
        float ssum = 0.f;
#pragma unroll
        for (int j = 0; j < OUTD; ++j) ssum += expf(zz[j] - m);
        float ls = logf(ssum);
#pragma unroll
        for (int j = 0; j < OUTD; ++j) out[g * OUTD + j] = zz[j] - m - ls;
    }
}

extern "C" void kernel_launch(void* const* d_in, const int* in_sizes, int n_in,
                              void* d_out, int out_size, void* d_ws, size_t ws_size,
                              hipStream_t stream) {
    const float* x   = (const float*)d_in[0];
    // d_in[1] = ptr (unused; structure is static)
    const float* Wl1 = (const float*)d_in[2];
    const float* bl1 = (const float*)d_in[3];
    const float* Wl2 = (const float*)d_in[4];
    const float* bl2 = (const float*)d_in[5];
    const float* Wg1 = (const float*)d_in[6];
    const float* bg1 = (const float*)d_in[7];
    const float* Wg2 = (const float*)d_in[8];
    const float* bg2 = (const float*)d_in[9];
    const float* Wb1 = (const float*)d_in[10];
    const float* bb1 = (const float*)d_in[11];
    const float* Wb2 = (const float*)d_in[12];
    const float* bb2 = (const float*)d_in[13];
    const float* Wd1 = (const float*)d_in[14];
    const float* bd1 = (const float*)d_in[15];
    const float* Wd2 = (const float*)d_in[16];
    const float* bd2 = (const float*)d_in[17];

    unsigned short* ws  = (unsigned short*)d_ws;
    unsigned short* agg = ws + AGG_OFF;

    prep_weights<<<352, 256, 0, stream>>>(Wl1, Wl2, Wg1, Wg2, Wb1, Wb2, ws);
    local_mlp<<<NG * 8, 256, 0, stream>>>(x, ws, bl1, bl2, agg);
    global_decoder<<<NG, 256, 0, stream>>>(ws, agg, bg1, bg2, bb1, bb2,
                                           Wd1, bd1, Wd2, bd2, (float*)d_out);
}

// Round 5
// 154.688 us; speedup vs baseline: 3.7764x; 1.0246x over previous
//
#include <hip/hip_runtime.h>
#include <stdint.h>

// Problem constants (static per reference)
#define NG    256    // graphs
#define NPG   128    // nodes per graph
#define PP    8      // perturbations
#define IND   64     // input dim
#define HID   128    // hidden
#define OUTD  10     // classes

typedef short bf16x8 __attribute__((ext_vector_type(8)));
typedef float f32x4  __attribute__((ext_vector_type(4)));

// RNE f32->bf16 (bit trick) — the verified-correct conversion on this path.
static __device__ __forceinline__ unsigned short f2bf(float f) {
    unsigned int u = __float_as_uint(f);
    u += 0x7FFFu + ((u >> 16) & 1u);
    return (unsigned short)(u >> 16);
}

static __device__ __forceinline__ f32x4 mfma16(bf16x8 a, bf16x8 b, f32x4 c) {
    return __builtin_amdgcn_mfma_f32_16x16x32_bf16(a, b, c, 0, 0, 0);
}

// ws layout (shorts):
//   [0)      W1t  128x64   (Wt[out][in])
//   [8192)   W2t  128x128
//   [24576)  Wg1t 128x128
//   [40960)  Wg2t 128x128
//   [57344)  Wb1t 128x128
//   [73728)  Wb2t 128x128
//   [90112)  agg  32768x128 bf16 (phase-A output)
#define AGG_OFF   90112

#define LSTR 136   // bf16 LDS row stride for 128-col tiles (272 B): 68 words
                   // == 4 mod 32 -> only 2-way bank aliasing (free)
#define XBS  72    // x-slab stride (64 cols + pad): 36 words == 4 mod 32, same
#define HSTR 136   // h1 stride: MUST be >= 128 (round-3/4 bug: 72 overflowed
                   // into the next row for cols >= 72 -> silent corruption)

// ---------------------------------------------------------------------------
// Kernel 0: convert + transpose weights (coalesced writes; src stays in L2)
// ---------------------------------------------------------------------------
__global__ void prep_weights(const float* __restrict__ Wl1, const float* __restrict__ Wl2,
                             const float* __restrict__ Wg1, const float* __restrict__ Wg2,
                             const float* __restrict__ Wb1, const float* __restrict__ Wb2,
                             unsigned short* __restrict__ ws) {
    int e = blockIdx.x * blockDim.x + threadIdx.x;
    if (e < 8192) {
        int n = e >> 6, k = e & 63;
        ws[e] = f2bf(Wl1[k * HID + n]);
        return;
    }
    int e2 = e - 8192;
    int m = e2 >> 14;
    int idx = e2 & 16383;
    int n = idx >> 7, k = idx & 127;
    const float* src;
    if      (m == 0) src = Wl2;
    else if (m == 1) src = Wg1;
    else if (m == 2) src = Wg2;
    else if (m == 3) src = Wb1;
    else             src = Wb2;
    ws[8192 + m * 16384 + idx] = f2bf(src[k * HID + n]);
}

// ---------------------------------------------------------------------------
// Kernel 1 (phase A): block = (g, 16-node tile). 2048 blocks x 256 threads.
//  - x staged to LDS as bf16 ONCE (float4 -> f2bf x4 -> 8B ds_write): kills
//    the 4x-redundant per-wave conversion of the round-2 p-loop.
//  - p-loop split in two halves of 4: layer 1 for 4 p's into a 64-row h1
//    (HSTR=136 stride -> no overflow), barrier, layer 2 for those 4 p's,
//    barrier. 6 barriers total (vs 10), MFMA in runs of 16/32 per wave.
//  - LDS 18432 + 17408 = 35840 B -> launch_bounds(256,4): 4 blocks/CU.
//  - All f32->bf16 via f2bf (RNE): bit-identical to the round-2 passing path.
// ---------------------------------------------------------------------------
__global__ __launch_bounds__(256, 4) void local_mlp(
    const float* __restrict__ x,
    const unsigned short* __restrict__ wt,
    const float* __restrict__ bl1, const float* __restrict__ bl2,
    unsigned short* __restrict__ aggbuf)
{
    __shared__ unsigned short xb[128 * XBS];   // 18432 B, x slab in bf16
    __shared__ unsigned short h1[64 * HSTR];   // 17408 B, layer-1 out (4 p's)

    const int g    = blockIdx.x >> 3;
    const int nt   = blockIdx.x & 7;
    const int tid  = threadIdx.x;
    const int wave = tid >> 6;
    const int lane = tid & 63;
    const int q    = lane >> 4;
    const int r    = lane & 15;
    const int ot0  = wave * 2;     // this wave's out-tiles

    // ---- stage x slab (128 rows x 64 f32 = 32 KB) as bf16, converted once ----
    // LDS row s = p*16+rr  <->  global row g*1024 + p*128 + nt*16 + rr
    {
        const float* xg = x + ((size_t)g * 1024 + nt * 16) * IND;
#pragma unroll
        for (int it = 0; it < 8; ++it) {
            int e = it * 1024 + tid * 4;       // element index in the slab
            int s = e >> 6, col = e & 63;
            int p = s >> 4, rr = s & 15;
            float4 v = *(const float4*)(xg + ((size_t)(p * 128 + rr)) * IND + col);
            ushort4 w4;
            w4.x = f2bf(v.x);
            w4.y = f2bf(v.y);
            w4.z = f2bf(v.z);
            w4.w = f2bf(v.w);
            *(ushort4*)(&xb[s * XBS + col]) = w4;   // 8B store, col < 64 <= XBS
        }
    }

    // ---- weight fragments into registers (overlap with staging loads) ----
    bf16x8 w1f[2][2];
#pragma unroll
    for (int t = 0; t < 2; ++t)
#pragma unroll
        for (int ks = 0; ks < 2; ++ks)
            w1f[t][ks] = *(const bf16x8*)(wt + ((ot0 + t) * 16 + r) * 64 + ks * 32 + q * 8);

    const unsigned short* w2t = wt + 8192;
    bf16x8 w2f[2][4];
#pragma unroll
    for (int t = 0; t < 2; ++t)
#pragma unroll
        for (int ks = 0; ks < 4; ++ks)
            w2f[t][ks] = *(const bf16x8*)(w2t + ((ot0 + t) * 16 + r) * 128 + ks * 32 + q * 8);

    float4 b1s[2], b2s[2];
#pragma unroll
    for (int t = 0; t < 2; ++t) {
        int ob = (ot0 + t) * 16 + q * 4;
        b1s[t] = *(const float4*)(bl1 + ob);
        b2s[t] = *(const float4*)(bl2 + ob);
    }

    f32x4 agg0 = (f32x4){0.f, 0.f, 0.f, 0.f};
    f32x4 agg1 = (f32x4){0.f, 0.f, 0.f, 0.f};

    __syncthreads();   // xb fully staged

    // ---- two halves of 4 perturbations each ----
#pragma unroll
    for (int ph = 0; ph < 2; ++ph) {
        // layer 1 (K=64) for 4 p's: 16 MFMA/wave, writes h1 rows p4*16+r
#pragma unroll
        for (int p4 = 0; p4 < 4; ++p4) {
            const int p = ph * 4 + p4;
            f32x4 a0 = (f32x4){0.f, 0.f, 0.f, 0.f};
            f32x4 a1 = (f32x4){0.f, 0.f, 0.f, 0.f};
#pragma unroll
            for (int ks = 0; ks < 2; ++ks) {
                bf16x8 xf = *(const bf16x8*)(&xb[(p * 16 + r) * XBS + ks * 32 + q * 8]);
                a0 = mfma16(w1f[0][ks], xf, a0);
                a1 = mfma16(w1f[1][ks], xf, a1);
            }
            ushort4 v0, v1;
            v0.x = f2bf(fmaxf(a0[0] + b1s[0].x, 0.f));
            v0.y = f2bf(fmaxf(a0[1] + b1s[0].y, 0.f));
            v0.z = f2bf(fmaxf(a0[2] + b1s[0].z, 0.f));
            v0.w = f2bf(fmaxf(a0[3] + b1s[0].w, 0.f));
            v1.x = f2bf(fmaxf(a1[0] + b1s[1].x, 0.f));
            v1.y = f2bf(fmaxf(a1[1] + b1s[1].y, 0.f));
            v1.z = f2bf(fmaxf(a1[2] + b1s[1].z, 0.f));
            v1.w = f2bf(fmaxf(a1[3] + b1s[1].w, 0.f));
            *(ushort4*)(&h1[(p4 * 16 + r) * HSTR + (ot0 + 0) * 16 + q * 4]) = v0;
            *(ushort4*)(&h1[(p4 * 16 + r) * HSTR + (ot0 + 1) * 16 + q * 4]) = v1;
        }

        __syncthreads();   // h1 (64 rows x 128 cols) complete

        // layer 2 (K=128) for the same 4 p's, relu-accumulate into agg
#pragma unroll
        for (int p4 = 0; p4 < 4; ++p4) {
            f32x4 c0 = (f32x4){0.f, 0.f, 0.f, 0.f};
            f32x4 c1 = (f32x4){0.f, 0.f, 0.f, 0.f};
#pragma unroll
            for (int ks = 0; ks < 4; ++ks) {
                bf16x8 hf = *(const bf16x8*)(&h1[(p4 * 16 + r) * HSTR + ks * 32 + q * 8]);
                c0 = mfma16(w2f[0][ks], hf, c0);
                c1 = mfma16(w2f[1][ks], hf, c1);
            }
            agg0[0] += fmaxf(c0[0] + b2s[0].x, 0.f);
            agg0[1] += fmaxf(c0[1] + b2s[0].y, 0.f);
            agg0[2] += fmaxf(c0[2] + b2s[0].z, 0.f);
            agg0[3] += fmaxf(c0[3] + b2s[0].w, 0.f);
            agg1[0] += fmaxf(c1[0] + b2s[1].x, 0.f);
            agg1[1] += fmaxf(c1[1] + b2s[1].y, 0.f);
            agg1[2] += fmaxf(c1[2] + b2s[1].z, 0.f);
            agg1[3] += fmaxf(c1[3] + b2s[1].w, 0.f);
        }

        __syncthreads();   // all waves done reading h1 before next half rewrites
    }

    // stage agg (bf16) in h1 rows 0..15, then coalesced 16B writeback
    {
        ushort4 v0, v1;
        v0.x = f2bf(agg0[0]);
        v0.y = f2bf(agg0[1]);
        v0.z = f2bf(agg0[2]);
        v0.w = f2bf(agg0[3]);
        v1.x = f2bf(agg1[0]);
        v1.y = f2bf(agg1[1]);
        v1.z = f2bf(agg1[2]);
        v1.w = f2bf(agg1[3]);
        *(ushort4*)(&h1[r * HSTR + (ot0 + 0) * 16 + q * 4]) = v0;
        *(ushort4*)(&h1[r * HSTR + (ot0 + 1) * 16 + q * 4]) = v1;
    }
    __syncthreads();
    {
        int row = tid >> 4, c8 = (tid & 15) * 8;
        bf16x8 v = *(const bf16x8*)(&h1[row * HSTR + c8]);
        *(bf16x8*)(aggbuf + ((size_t)(g * NPG + nt * 16 + row)) * HID + c8) = v;
    }
}

// ---------------------------------------------------------------------------
// Kernel 2: 4x (Linear+ReLU) on FULL graphs (128 rows in LDS), then
// global_add_pool + decoder + log_softmax in the same block.
// 256 blocks x 256 threads; wave w owns output columns [32w, 32w+32).
// ---------------------------------------------------------------------------
__global__ __launch_bounds__(256) void global_decoder(
    const unsigned short* __restrict__ wt,
    const unsigned short* __restrict__ aggbuf,
    const float* __restrict__ bg1, const float* __restrict__ bg2,
    const float* __restrict__ bb1, const float* __restrict__ bb2,
    const float* __restrict__ Wd1, const float* __restrict__ bd1,
    const float* __restrict__ Wd2, const float* __restrict__ bd2,
    float* __restrict__ out)
{
    __shared__ unsigned short buf0[128 * LSTR];   // 34816 B
    __shared__ unsigned short buf1[128 * LSTR];   // 34816 B
    __shared__ float pool[HID];
    __shared__ float z[64];
    __shared__ float zz[OUTD];

    const int g    = blockIdx.x;
    const int tid  = threadIdx.x;
    const int wave = tid >> 6;
    const int lane = tid & 63;
    const int q    = lane >> 4;
    const int r    = lane & 15;
    const int ot0  = wave * 2;

    // stage this graph's 128 agg rows (32 KB) coalesced
    const unsigned short* ag = aggbuf + (size_t)g * NPG * HID;
#pragma unroll
    for (int it = 0; it < 8; ++it) {
        int c = tid + it * 256;
        int row = c >> 4, c8 = (c & 15) * 8;
        *(bf16x8*)(buf0 + row * LSTR + c8) = *(const bf16x8*)(ag + (size_t)row * HID + c8);
    }
    __syncthreads();

    int cur = 0;
#pragma unroll
    for (int l = 0; l < 4; ++l) {
        const unsigned short* wl = wt + 24576 + l * 16384;
        const float* bl = (l == 0) ? bg1 : (l == 1) ? bg2 : (l == 2) ? bb1 : bb2;

        bf16x8 wf[2][4];
#pragma unroll
        for (int t = 0; t < 2; ++t)
#pragma unroll
            for (int ks = 0; ks < 4; ++ks)
                wf[t][ks] = *(const bf16x8*)(wl + ((ot0 + t) * 16 + r) * 128 + ks * 32 + q * 8);

        unsigned short* Xb = cur ? buf1 : buf0;
        unsigned short* Yb = cur ? buf0 : buf1;

        f32x4 acc[2][8];
#pragma unroll
        for (int t = 0; t < 2; ++t)
#pragma unroll
            for (int j = 0; j < 8; ++j)
                acc[t][j] = (f32x4){0.f, 0.f, 0.f, 0.f};

#pragma unroll
        for (int ks = 0; ks < 4; ++ks) {
#pragma unroll
            for (int j = 0; j < 8; ++j) {
                int row = j * 16 + r;
                bf16x8 xf = *(const bf16x8*)(Xb + row * LSTR + ks * 32 + q * 8);
                acc[0][j] = mfma16(wf[0][ks], xf, acc[0][j]);
                acc[1][j] = mfma16(wf[1][ks], xf, acc[1][j]);
            }
        }

        if (l < 3) {
#pragma unroll
            for (int t = 0; t < 2; ++t) {
                int ob = (ot0 + t) * 16 + q * 4;
                float4 bs = *(const float4*)(bl + ob);
#pragma unroll
                for (int j = 0; j < 8; ++j) {
                    int row = j * 16 + r;
                    ushort4 v;
                    v.x = f2bf(fmaxf(acc[t][j][0] + bs.x, 0.f));
                    v.y = f2bf(fmaxf(acc[t][j][1] + bs.y, 0.f));
                    v.z = f2bf(fmaxf(acc[t][j][2] + bs.z, 0.f));
                    v.w = f2bf(fmaxf(acc[t][j][3] + bs.w, 0.f));
                    *(ushort4*)(Yb + row * LSTR + ob) = v;
                }
            }
            __syncthreads();
            cur ^= 1;
        } else {
            float s[2][4];
#pragma unroll
            for (int t = 0; t < 2; ++t) {
                int ob = (ot0 + t) * 16 + q * 4;
                float4 bs = *(const float4*)(bl + ob);
                s[t][0] = s[t][1] = s[t][2] = s[t][3] = 0.f;
#pragma unroll
                for (int j = 0; j < 8; ++j) {
                    s[t][0] += fmaxf(acc[t][j][0] + bs.x, 0.f);
                    s[t][1] += fmaxf(acc[t][j][1] + bs.y, 0.f);
                    s[t][2] += fmaxf(acc[t][j][2] + bs.z, 0.f);
                    s[t][3] += fmaxf(acc[t][j][3] + bs.w, 0.f);
                }
            }
#pragma unroll
            for (int m = 1; m < 16; m <<= 1) {
#pragma unroll
                for (int t = 0; t < 2; ++t)
#pragma unroll
                    for (int i = 0; i < 4; ++i)
                        s[t][i] += __shfl_xor(s[t][i], m, 64);
            }
            if (r == 0) {
#pragma unroll
                for (int t = 0; t < 2; ++t)
#pragma unroll
                    for (int i = 0; i < 4; ++i)
                        pool[(ot0 + t) * 16 + q * 4 + i] = s[t][i];  // exclusive cols/wave
            }
        }
    }
    __syncthreads();

    // ---- decoder + log_softmax ----
    if (tid < 64) {
        float a0 = bd1[tid], a1 = 0.f, a2 = 0.f, a3 = 0.f;
#pragma unroll
        for (int k = 0; k < 128; k += 4) {
            a0 += pool[k]     * Wd1[(k)     * 64 + tid];
            a1 += pool[k + 1] * Wd1[(k + 1) * 64 + tid];
            a2 += pool[k + 2] * Wd1[(k + 2) * 64 + tid];
            a3 += pool[k + 3] * Wd1[(k + 3) * 64 + tid];
        }
        z[tid] = fmaxf((a0 + a1) + (a2 + a3), 0.f);
    }
    __syncthreads();
    if (tid < OUTD) {
        float b0 = bd2[tid], b1 = 0.f;
#pragma unroll
        for (int k = 0; k < 64; k += 2) {
            b0 += z[k]     * Wd2[(k)     * OUTD + tid];
            b1 += z[k + 1] * Wd2[(k + 1) * OUTD + tid];
        }
        zz[tid] = b0 + b1;
    }
    __syncthreads();
    if (tid == 0) {
        float m = -1e30f;
#pragma unroll
        for (int j = 0; j < OUTD; ++j) m = fmaxf(m, zz[j]);
        float ssum = 0.f;
#pragma unroll
        for (int j = 0; j < OUTD; ++j) ssum += expf(zz[j] - m);
        float ls = logf(ssum);
#pragma unroll
        for (int j = 0; j < OUTD; ++j) out[g * OUTD + j] = zz[j] - m - ls;
    }
}

extern "C" void kernel_launch(void* const* d_in, const int* in_sizes, int n_in,
                              void* d_out, int out_size, void* d_ws, size_t ws_size,
                              hipStream_t stream) {
    const float* x   = (const float*)d_in[0];
    // d_in[1] = ptr (unused; structure is static)
    const float* Wl1 = (const float*)d_in[2];
    const float* bl1 = (const float*)d_in[3];
    const float* Wl2 = (const float*)d_in[4];
    const float* bl2 = (const float*)d_in[5];
    const float* Wg1 = (const float*)d_in[6];
    const float* bg1 = (const float*)d_in[7];
    const float* Wg2 = (const float*)d_in[8];
    const float* bg2 = (const float*)d_in[9];
    const float* Wb1 = (const float*)d_in[10];
    const float* bb1 = (const float*)d_in[11];
    const float* Wb2 = (const float*)d_in[12];
    const float* bb2 = (const float*)d_in[13];
    const float* Wd1 = (const float*)d_in[14];
    const float* bd1 = (const float*)d_in[15];
    const float* Wd2 = (const float*)d_in[16];
    const float* bd2 = (const float*)d_in[17];

    unsigned short* ws  = (unsigned short*)d_ws;
    unsigned short* agg = ws + AGG_OFF;

    prep_weights<<<352, 256, 0, stream>>>(Wl1, Wl2, Wg1, Wg2, Wb1, Wb2, ws);
    local_mlp<<<NG * 8, 256, 0, stream>>>(x, ws, bl1, bl2, agg);
    global_decoder<<<NG, 256, 0, stream>>>(ws, agg, bg1, bg2, bb1, bb2,
                                           Wd1, bd1, Wd2, bd2, (float*)d_out);
}

// Round 6
// 143.216 us; speedup vs baseline: 4.0789x; 1.0801x over previous
//
#include <hip/hip_runtime.h>
#include <stdint.h>

// Problem constants (static per reference)
#define NG    256    // graphs
#define NPG   128    // nodes per graph
#define PP    8      // perturbations
#define IND   64     // input dim
#define HID   128    // hidden
#define OUTD  10     // classes

typedef short bf16x8 __attribute__((ext_vector_type(8)));
typedef float f32x4  __attribute__((ext_vector_type(4)));

// RNE f32->bf16 (bit trick) — the verified-correct conversion on this path.
// (Round-3 showed inline-asm v_cvt_pk_bf16_f32 does NOT match this rounding.)
static __device__ __forceinline__ unsigned short f2bf(float f) {
    unsigned int u = __float_as_uint(f);
    u += 0x7FFFu + ((u >> 16) & 1u);
    return (unsigned short)(u >> 16);
}

static __device__ __forceinline__ f32x4 mfma16(bf16x8 a, bf16x8 b, f32x4 c) {
    return __builtin_amdgcn_mfma_f32_16x16x32_bf16(a, b, c, 0, 0, 0);
}

// ws layout (shorts) — weights only now (no agg round-trip):
//   [0)      W1t  128x64   (Wt[out][in])
//   [8192)   W2t  128x128
//   [24576)  Wg1t 128x128
//   [40960)  Wg2t 128x128
//   [57344)  Wb1t 128x128
//   [73728)  Wb2t 128x128

#define LSTR 136   // bf16 LDS row stride for 128-col tiles (272 B): 68 words
                   // == 4 mod 32 -> only 2-way bank aliasing (free)
#define XBS  72    // x-slab stride (64 cols + pad): 36 words == 4 mod 32, same

// ---------------------------------------------------------------------------
// Kernel 0: convert + transpose weights (coalesced writes; src stays in L2)
// ---------------------------------------------------------------------------
__global__ void prep_weights(const float* __restrict__ Wl1, const float* __restrict__ Wl2,
                             const float* __restrict__ Wg1, const float* __restrict__ Wg2,
                             const float* __restrict__ Wb1, const float* __restrict__ Wb2,
                             unsigned short* __restrict__ ws) {
    int e = blockIdx.x * blockDim.x + threadIdx.x;
    if (e < 8192) {
        int n = e >> 6, k = e & 63;
        ws[e] = f2bf(Wl1[k * HID + n]);
        return;
    }
    int e2 = e - 8192;
    int m = e2 >> 14;
    int idx = e2 & 16383;
    int n = idx >> 7, k = idx & 127;
    const float* src;
    if      (m == 0) src = Wl2;
    else if (m == 1) src = Wg1;
    else if (m == 2) src = Wg2;
    else if (m == 3) src = Wb1;
    else             src = Wb2;
    ws[8192 + m * 16384 + idx] = f2bf(src[k * HID + n]);
}

// ---------------------------------------------------------------------------
// Fused kernel: ONE BLOCK PER GRAPH (256 blocks x 512 threads = 8 waves).
// Fence-free fusion: all producer/consumer edges (node tiles -> agg -> global
// layers -> pool -> decoder) live inside one block, synced by __syncthreads.
// Phase A: loop over the graph's 8 node-tiles; x prefetched 2 tiles deep
// (global->reg early, f2bf->LDS late); layer1 -> h1 -> layer2 -> agg in LDS.
// Phase B: 4x(Linear+ReLU) ping-ponging aggL <-> bufB (bufB aliases dead xb),
// then pool + decoder + log_softmax. Arithmetic is a 1:1 transplant of the
// round-5 passing kernels (same ops, same order, same f2bf sites).
// LDS 107328 B -> 1 block/CU (gfx950 LDS is 160 KB; >64KB static works,
// cf. the 128 KiB 8-phase GEMM template).
// ---------------------------------------------------------------------------
__global__ __launch_bounds__(512) void graph_fused(
    const float* __restrict__ x,
    const unsigned short* __restrict__ wt,
    const float* __restrict__ bl1, const float* __restrict__ bl2,
    const float* __restrict__ bg1, const float* __restrict__ bg2,
    const float* __restrict__ bb1, const float* __restrict__ bb2,
    const float* __restrict__ Wd1, const float* __restrict__ bd1,
    const float* __restrict__ Wd2, const float* __restrict__ bd2,
    float* __restrict__ out)
{
    // LDS map (bytes):
    //   [0)      xb0 128*XBS shorts (18432) \  phase A x dbuf; aliased by
    //   [18432)  xb1 128*XBS shorts (18432) /  bufB (34816 B) in phase B
    //   [36864)  h1   128*LSTR shorts (34816)
    //   [71680)  aggL 128*LSTR shorts (34816)
    //   [106496) pool 128 f32 (512)
    //   [107008) z    64 f32  (256)
    //   [107264) zz   16 f32  (64)
    __shared__ __align__(16) unsigned char smem[107328];
    unsigned short* xb0  = (unsigned short*)(smem);
    unsigned short* xb1  = (unsigned short*)(smem + 18432);
    unsigned short* h1   = (unsigned short*)(smem + 36864);
    unsigned short* aggL = (unsigned short*)(smem + 71680);
    unsigned short* bufB = (unsigned short*)(smem);            // phase-B ping
    float* pool = (float*)(smem + 106496);
    float* z    = (float*)(smem + 107008);
    float* zz   = (float*)(smem + 107264);

    const int g    = blockIdx.x;
    const int tid  = threadIdx.x;
    const int wave = tid >> 6;     // 0..7
    const int lane = tid & 63;
    const int q    = lane >> 4;
    const int r    = lane & 15;
    const int ot   = wave;         // each wave owns output cols [16*ot, 16*ot+16)

    const float* xg = x + (size_t)g * (NPG * PP) * IND;

    // ---- per-thread staging geometry: 8192 elems/tile, 16 per thread ----
    int sIt[4], cIt[4], gRow[4];
#pragma unroll
    for (int it = 0; it < 4; ++it) {
        int e = it * 2048 + tid * 4;       // element index in the tile slab
        int s = e >> 6;                    // LDS row (p*16 + rr)
        sIt[it]  = s;
        cIt[it]  = e & 63;
        gRow[it] = (s >> 4) * 128 + (s & 15);   // global row sans nt*16
    }
    float4 ld[4];

#define ISSUE(t)                                                              \
    do {                                                                      \
        _Pragma("unroll")                                                     \
        for (int it = 0; it < 4; ++it)                                        \
            ld[it] = *(const float4*)(xg + (size_t)(gRow[it] + (t) * 16) * IND + cIt[it]); \
    } while (0)

#define XWRITE(dst)                                                           \
    do {                                                                      \
        _Pragma("unroll")                                                     \
        for (int it = 0; it < 4; ++it) {                                      \
            ushort4 w4;                                                       \
            w4.x = f2bf(ld[it].x); w4.y = f2bf(ld[it].y);                     \
            w4.z = f2bf(ld[it].z); w4.w = f2bf(ld[it].w);                     \
            *(ushort4*)(&(dst)[sIt[it] * XBS + cIt[it]]) = w4;                \
        }                                                                     \
    } while (0)

    // ---- weight fragments (loads overlap the tile-0 staging) ----
    bf16x8 w1f[2];
#pragma unroll
    for (int ks = 0; ks < 2; ++ks)
        w1f[ks] = *(const bf16x8*)(wt + (ot * 16 + r) * 64 + ks * 32 + q * 8);

    const unsigned short* w2t = wt + 8192;
    bf16x8 w2f[4];
#pragma unroll
    for (int ks = 0; ks < 4; ++ks)
        w2f[ks] = *(const bf16x8*)(w2t + (ot * 16 + r) * 128 + ks * 32 + q * 8);

    const float4 b1s = *(const float4*)(bl1 + ot * 16 + q * 4);
    const float4 b2s = *(const float4*)(bl2 + ot * 16 + q * 4);

    // ---- prologue: tile 0 staged, tile 1 in flight ----
    ISSUE(0);
    XWRITE(xb0);
    ISSUE(1);
    __syncthreads();

    // ======================= phase A: 8 node-tiles =========================
    for (int nt = 0; nt < 8; ++nt) {
        unsigned short* xcur = (nt & 1) ? xb1 : xb0;

        // layer 1 (K=64) for all 8 perturbations of this tile
#pragma unroll
        for (int p = 0; p < PP; ++p) {
            f32x4 a0 = (f32x4){0.f, 0.f, 0.f, 0.f};
#pragma unroll
            for (int ks = 0; ks < 2; ++ks) {
                bf16x8 xf = *(const bf16x8*)(&xcur[(p * 16 + r) * XBS + ks * 32 + q * 8]);
                a0 = mfma16(w1f[ks], xf, a0);
            }
            ushort4 v0;
            v0.x = f2bf(fmaxf(a0[0] + b1s.x, 0.f));
            v0.y = f2bf(fmaxf(a0[1] + b1s.y, 0.f));
            v0.z = f2bf(fmaxf(a0[2] + b1s.z, 0.f));
            v0.w = f2bf(fmaxf(a0[3] + b1s.w, 0.f));
            *(ushort4*)(&h1[(p * 16 + r) * LSTR + ot * 16 + q * 4]) = v0;
        }
        __syncthreads();   // h1 complete (all 128 cols from all 8 waves)

        // layer 2 (K=128), relu-accumulate over perturbations
        f32x4 agg0 = (f32x4){0.f, 0.f, 0.f, 0.f};
#pragma unroll
        for (int p = 0; p < PP; ++p) {
            f32x4 c0 = (f32x4){0.f, 0.f, 0.f, 0.f};
#pragma unroll
            for (int ks = 0; ks < 4; ++ks) {
                bf16x8 hf = *(const bf16x8*)(&h1[(p * 16 + r) * LSTR + ks * 32 + q * 8]);
                c0 = mfma16(w2f[ks], hf, c0);
            }
            agg0[0] += fmaxf(c0[0] + b2s.x, 0.f);
            agg0[1] += fmaxf(c0[1] + b2s.y, 0.f);
            agg0[2] += fmaxf(c0[2] + b2s.z, 0.f);
            agg0[3] += fmaxf(c0[3] + b2s.w, 0.f);
        }
        // agg for node rows nt*16..+16: exclusive (r, col) region per lane
        {
            ushort4 av;
            av.x = f2bf(agg0[0]);
            av.y = f2bf(agg0[1]);
            av.z = f2bf(agg0[2]);
            av.w = f2bf(agg0[3]);
            *(ushort4*)(&aggL[(nt * 16 + r) * LSTR + ot * 16 + q * 4]) = av;
        }

        // stage next tile's x into the other buffer (regs already loaded),
        // then refill regs two tiles ahead. Safe: the end-of-previous-tile
        // barrier guarantees nobody still reads xb[(nt+1)&1].
        if (nt < 7) {
            if (nt & 1) XWRITE(xb0); else XWRITE(xb1);
        }
        if (nt < 6) ISSUE(nt + 2);
        __syncthreads();   // h1 reuse + next xb ready
    }

    // ================= phase B: 4x (Linear+ReLU) + pool ====================
    int cur = 0;
#pragma unroll
    for (int l = 0; l < 4; ++l) {
        const unsigned short* wl = wt + 24576 + l * 16384;
        const float* bl = (l == 0) ? bg1 : (l == 1) ? bg2 : (l == 2) ? bb1 : bb2;

        bf16x8 wf[4];
#pragma unroll
        for (int ks = 0; ks < 4; ++ks)
            wf[ks] = *(const bf16x8*)(wl + (ot * 16 + r) * 128 + ks * 32 + q * 8);

        unsigned short* Xb = cur ? bufB : aggL;
        unsigned short* Yb = cur ? aggL : bufB;

        f32x4 acc[8];
#pragma unroll
        for (int j = 0; j < 8; ++j)
            acc[j] = (f32x4){0.f, 0.f, 0.f, 0.f};

#pragma unroll
        for (int ks = 0; ks < 4; ++ks) {
#pragma unroll
            for (int j = 0; j < 8; ++j) {
                bf16x8 xf = *(const bf16x8*)(&Xb[(j * 16 + r) * LSTR + ks * 32 + q * 8]);
                acc[j] = mfma16(wf[ks], xf, acc[j]);
            }
        }

        if (l < 3) {
            float4 bs = *(const float4*)(bl + ot * 16 + q * 4);
#pragma unroll
            for (int j = 0; j < 8; ++j) {
                ushort4 v;
                v.x = f2bf(fmaxf(acc[j][0] + bs.x, 0.f));
                v.y = f2bf(fmaxf(acc[j][1] + bs.y, 0.f));
                v.z = f2bf(fmaxf(acc[j][2] + bs.z, 0.f));
                v.w = f2bf(fmaxf(acc[j][3] + bs.w, 0.f));
                *(ushort4*)(&Yb[(j * 16 + r) * LSTR + ot * 16 + q * 4]) = v;
            }
            __syncthreads();
            cur ^= 1;
        } else {
            float4 bs = *(const float4*)(bl + ot * 16 + q * 4);
            float s0 = 0.f, s1 = 0.f, s2 = 0.f, s3 = 0.f;
#pragma unroll
            for (int j = 0; j < 8; ++j) {
                s0 += fmaxf(acc[j][0] + bs.x, 0.f);
                s1 += fmaxf(acc[j][1] + bs.y, 0.f);
                s2 += fmaxf(acc[j][2] + bs.z, 0.f);
                s3 += fmaxf(acc[j][3] + bs.w, 0.f);
            }
#pragma unroll
            for (int m = 1; m < 16; m <<= 1) {
                s0 += __shfl_xor(s0, m, 64);
                s1 += __shfl_xor(s1, m, 64);
                s2 += __shfl_xor(s2, m, 64);
                s3 += __shfl_xor(s3, m, 64);
            }
            if (r == 0) {
                pool[ot * 16 + q * 4 + 0] = s0;   // exclusive cols per wave
                pool[ot * 16 + q * 4 + 1] = s1;
                pool[ot * 16 + q * 4 + 2] = s2;
                pool[ot * 16 + q * 4 + 3] = s3;
            }
        }
    }
    __syncthreads();

    // ===================== decoder + log_softmax ===========================
    if (tid < 64) {
        float a0 = bd1[tid], a1 = 0.f, a2 = 0.f, a3 = 0.f;
#pragma unroll
        for (int k = 0; k < 128; k += 4) {
            a0 += pool[k]     * Wd1[(k)     * 64 + tid];
            a1 += pool[k + 1] * Wd1[(k + 1) * 64 + tid];
            a2 += pool[k + 2] * Wd1[(k + 2) * 64 + tid];
            a3 += pool[k + 3] * Wd1[(k + 3) * 64 + tid];
        }
        z[tid] = fmaxf((a0 + a1) + (a2 + a3), 0.f);
    }
    __syncthreads();
    if (tid < OUTD) {
        float b0 = bd2[tid], b1 = 0.f;
#pragma unroll
        for (int k = 0; k < 64; k += 2) {
            b0 += z[k]     * Wd2[(k)     * OUTD + tid];
            b1 += z[k + 1] * Wd2[(k + 1) * OUTD + tid];
        }
        zz[tid] = b0 + b1;
    }
    __syncthreads();
    if (tid == 0) {
        float m = -1e30f;
#pragma unroll
        for (int j = 0; j < OUTD; ++j) m = fmaxf(m, zz[j]);
        float ssum = 0.f;
#pragma unroll
        for (int j = 0; j < OUTD; ++j) ssum += expf(zz[j] - m);
        float ls = logf(ssum);
#pragma unroll
        for (int j = 0; j < OUTD; ++j) out[g * OUTD + j] = zz[j] - m - ls;
    }
#undef ISSUE
#undef XWRITE
}

extern "C" void kernel_launch(void* const* d_in, const int* in_sizes, int n_in,
                              void* d_out, int out_size, void* d_ws, size_t ws_size,
                              hipStream_t stream) {
    const float* x   = (const float*)d_in[0];
    // d_in[1] = ptr (unused; structure is static)
    const float* Wl1 = (const float*)d_in[2];
    const float* bl1 = (const float*)d_in[3];
    const float* Wl2 = (const float*)d_in[4];
    const float* bl2 = (const float*)d_in[5];
    const float* Wg1 = (const float*)d_in[6];
    const float* bg1 = (const float*)d_in[7];
    const float* Wg2 = (const float*)d_in[8];
    const float* bg2 = (const float*)d_in[9];
    const float* Wb1 = (const float*)d_in[10];
    const float* bb1 = (const float*)d_in[11];
    const float* Wb2 = (const float*)d_in[12];
    const float* bb2 = (const float*)d_in[13];
    const float* Wd1 = (const float*)d_in[14];
    const float* bd1 = (const float*)d_in[15];
    const float* Wd2 = (const float*)d_in[16];
    const float* bd2 = (const float*)d_in[17];

    unsigned short* ws = (unsigned short*)d_ws;

    prep_weights<<<352, 256, 0, stream>>>(Wl1, Wl2, Wg1, Wg2, Wb1, Wb2, ws);
    graph_fused<<<NG, 512, 0, stream>>>(x, ws, bl1, bl2, bg1, bg2, bb1, bb2,
                                        Wd1, bd1, Wd2, bd2, (float*)d_out);
}